// Round 4
// baseline (351.981 us; speedup 1.0000x reference)
//
#include <hip/hip_runtime.h>
#include <math.h>

#define NE 8
#define NH 2048
#define NI 1024
#define NT 512
#define NTOPK 2
#define NR 16
#define NGROUP 64
#define NPAIR (NT*NTOPK)   // 1024

typedef short bf16x8 __attribute__((ext_vector_type(8)));
typedef float f32x16 __attribute__((ext_vector_type(16)));
typedef unsigned int u32;

#define MFMA32 __builtin_amdgcn_mfma_f32_32x32x16_bf16

__device__ const float NF4_TAB[16] = {
    -1.0f, -0.6961928009986877f, -0.5250730514526367f, -0.39491748809814453f,
    -0.28444138169288635f, -0.18477343022823334f, -0.09105003625154495f, 0.0f,
    0.07958029955625534f, 0.16093020141124725f, 0.24611230194568634f,
    0.33791524171829224f, 0.44070982933044434f, 0.5626170039176941f,
    0.7229568362236328f, 1.0f};

// ---------------- workspace layout (bytes) ----------------
#define OFF_EXPOFF 0         // int[16]
#define OFF_TOK    256       // int[1024]
#define OFF_EXP    4352      // int[1024]
#define OFF_W      8448      // float[1024]
#define OFF_XAG    12544     // ushort[1024*16] bf16
#define OFF_XAU    45312     // ushort[1024*16]
#define OFF_HA     78080     // ushort[1024*16]
#define OFF_XB     131072    // ushort[512*2048] bf16 x (2 MB)
#define OFF_HBUF   2228224   // ushort[1024*1024] bf16 h (2 MB)

__device__ inline u32 f2bf(float f) {                 // round-half-up bf16 (low 16)
    return (__float_as_uint(f) + 0x8000u) >> 16;
}
__device__ inline u32 bfpack2(float a, float b) {     // two bf16 packed in a dword
    return ((__float_as_uint(a) + 0x8000u) >> 16) |
           ((__float_as_uint(b) + 0x8000u) & 0xFFFF0000u);
}
__device__ inline bf16x8 asbf(uint4 w) {
    union { uint4 u; bf16x8 b; } c; c.u = w; return c.b;
}
__device__ inline bf16x8 bfzero() { return asbf(make_uint4(0,0,0,0)); }

// async global->LDS staging. LDS dest = wave-uniform base + lane*size.
__device__ __forceinline__ void stage16(const void* g, void* l) {
    __builtin_amdgcn_global_load_lds(
        (const __attribute__((address_space(1))) u32*)g,
        (__attribute__((address_space(3))) u32*)l, 16, 0, 0);
}
__device__ __forceinline__ void stage4(const void* g, void* l) {
    __builtin_amdgcn_global_load_lds(
        (const __attribute__((address_space(1))) u32*)g,
        (__attribute__((address_space(3))) u32*)l, 4, 0, 0);
}

// -------- kernel 1: routing compaction (single block, 1024 threads) --------
__global__ __launch_bounds__(1024) void k_route(const int* __restrict__ idx,
                                                const float* __restrict__ w,
                                                int* expert_off, int* ptok,
                                                int* pexp, float* pw) {
    __shared__ int cnt[NE], off[NE + 1], cur[NE];
    int tid = threadIdx.x;            // 0..1023 == (t, slot)
    if (tid < NE) cnt[tid] = 0;
    __syncthreads();
    int e = idx[tid];
    float wt = w[tid];
    int t = tid >> 1;
    atomicAdd(&cnt[e], 1);
    __syncthreads();
    if (tid == 0) {
        off[0] = 0;
        for (int i = 0; i < NE; i++) off[i + 1] = off[i] + cnt[i];
    }
    __syncthreads();
    if (tid < NE) cur[tid] = off[tid];
    __syncthreads();
    int pos = atomicAdd(&cur[e], 1);
    ptok[pos] = t; pexp[pos] = e; pw[pos] = wt;
    if (tid <= NE) expert_off[tid] = off[tid];
}

// -------- kernel 2: x fp32 -> bf16 --------
__global__ __launch_bounds__(256) void k_xcvt(const float* __restrict__ x,
                                              unsigned short* __restrict__ xb) {
    int i = (blockIdx.x * 256 + threadIdx.x) * 8;
    float4 v0 = *(const float4*)(x + i);
    float4 v1 = *(const float4*)(x + i + 4);
    uint4 w;
    w.x = bfpack2(v0.x, v0.y); w.y = bfpack2(v0.z, v0.w);
    w.z = bfpack2(v1.x, v1.y); w.w = bfpack2(v1.z, v1.w);
    *(uint4*)(xb + i) = w;
}

// -------- kernel 3: xA_g[p][r], xA_u[p][r] (rank-16 projections, bf16 out) ----
__global__ __launch_bounds__(256) void k_xA(const float* __restrict__ x,
                                            const float* __restrict__ gA,
                                            const float* __restrict__ uA,
                                            const int* __restrict__ ptok,
                                            const int* __restrict__ pexp,
                                            unsigned short* __restrict__ xAg,
                                            unsigned short* __restrict__ xAu) {
    int p = blockIdx.x;
    int t = ptok[p], e = pexp[p];
    int tid = threadIdx.x;
    int r = tid & 15, ch = tid >> 4;          // 16 chunks of 128
    const float* xr = x + (size_t)t * NH;
    const float* gAr = gA + (size_t)e * NH * NR;
    const float* uAr = uA + (size_t)e * NH * NR;
    float sg = 0.f, su = 0.f;
    for (int j = ch * 128; j < ch * 128 + 128; ++j) {
        float xv = xr[j];
        sg += xv * gAr[j * NR + r];
        su += xv * uAr[j * NR + r];
    }
    __shared__ float red[2][16][16];
    red[0][ch][r] = sg; red[1][ch][r] = su;
    __syncthreads();
    for (int st = 8; st >= 1; st >>= 1) {
        if (ch < st) {
            red[0][ch][r] += red[0][ch + st][r];
            red[1][ch][r] += red[1][ch + st][r];
        }
        __syncthreads();
    }
    if (tid < 16) {
        xAg[p * NR + tid] = (unsigned short)f2bf(red[0][0][tid]);
        xAu[p * NR + tid] = (unsigned short)f2bf(red[1][0][tid]);
    }
}

// -------- kernel 4: gate/up grouped GEMM, m97-style async LDS staging --------
// block = 128 thr (2 waves). tile: 64 rows x 64 cols (wave owns 32 cols).
// K-step 64: codes + A-frags + scales staged via global_load_lds, dbuffered.
__global__ __launch_bounds__(128) void k_gateup_mfma(
    const unsigned short* __restrict__ xb,
    const int* __restrict__ gpk, const float* __restrict__ gsc,
    const int* __restrict__ upk, const float* __restrict__ usc,
    const float* __restrict__ gB, const float* __restrict__ uB,
    const unsigned short* __restrict__ xAg, const unsigned short* __restrict__ xAu,
    const int* __restrict__ expert_off, const int* __restrict__ ptok,
    unsigned short* __restrict__ hbuf)
{
    __shared__ float2 ptab[256];                 // 2 KB pair-dequant LUT
    __shared__ u32 rowoff[64];                   // x element offset per tile row
    __shared__ unsigned short afrag[2][4096];    // A in MFMA-frag order, 2x8 KB
    __shared__ u32 gcode[2][2048];               // 32 packed rows x 64 cols, 2x8 KB
    __shared__ u32 ucode[2][2048];
    __shared__ float gscl[2][64], uscl[2][64];

    int tid = threadIdx.x;
    int lane = tid & 63;
    int w = tid >> 6;                            // wave id (0/1)
    int q = lane >> 5;
    for (int i = tid; i < 256; i += 128)
        ptab[i] = make_float2(NF4_TAB[i & 15], NF4_TAB[(i >> 4) & 15]);

    int e = blockIdx.x;
    int c0 = blockIdx.y * 64;
    int off = expert_off[e];
    int cnt = expert_off[e + 1] - off;
    int cw = (w << 5) | (lane & 31);             // col within 64-tile
    int colg = c0 + cw;                          // global col

    const u32* gpk_u = (const u32*)gpk;
    const u32* upk_u = (const u32*)upk;
    const size_t pkb = (size_t)e * (NH / 2) * NI;
    const size_t scb = (size_t)e * (NH / NGROUP) * NI;

    __syncthreads();

    for (int s0 = blockIdx.z * 64; s0 < cnt; s0 += 128) {
        if (tid < 64) {
            int rid = s0 + tid; if (rid > cnt - 1) rid = cnt - 1;
            rowoff[tid] = (u32)ptok[off + rid] * (u32)NH;
        }
        __syncthreads();
        u32 ro0 = rowoff[lane & 31];
        u32 ro1 = rowoff[32 + (lane & 31)];

        f32x16 accg[2], accu[2];
        #pragma unroll
        for (int i = 0; i < 16; ++i) {
            accg[0][i] = 0.f; accg[1][i] = 0.f;
            accu[0][i] = 0.f; accu[1][i] = 0.f;
        }

        auto stage = [&](int b, int k0) {
            int kp0 = k0 >> 1;
            // codes: 8 groups per matrix; layout [row 0..31][col 0..63] dwords
            for (int g = w; g < 8; g += 2) {
                int slot = (g << 6) | lane;
                int row = slot >> 4, cc = (slot & 15) << 2;
                size_t src = pkb + (size_t)(kp0 + row) * NI + c0 + cc;
                stage16(gpk_u + src, &gcode[b][g << 8]);
                stage16(upk_u + src, &ucode[b][g << 8]);
            }
            // A frags: group fg = ks*2+mi; lane slot = its MFMA fragment
            for (int fg = w; fg < 8; fg += 2) {
                int ks = fg >> 1, mi = fg & 1;
                u32 ro = mi ? ro1 : ro0;
                stage16(xb + ro + k0 + (ks << 4) + ((lane >> 5) << 3),
                        &afrag[b][fg << 9]);
            }
            // scales (one row per K-step since KS==NGROUP)
            if (w == 0)
                stage4(gsc + scb + (size_t)(k0 >> 6) * NI + c0 + lane, &gscl[b][0]);
            else
                stage4(usc + scb + (size_t)(k0 >> 6) * NI + c0 + lane, &uscl[b][0]);
        };

        stage(0, 0);
        for (int s = 0; s < NH / 64; ++s) {
            __syncthreads();                       // drain current stage
            if (s + 1 < NH / 64) stage((s + 1) & 1, (s + 1) * 64);
            int b = s & 1;
            float scg = gscl[b][cw], scu = uscl[b][cw];
            #pragma unroll
            for (int ks = 0; ks < 4; ++ks) {
                bf16x8 a0 = *(const bf16x8*)&afrag[b][((ks << 1) | 0) * 512 + lane * 8];
                bf16x8 a1 = *(const bf16x8*)&afrag[b][((ks << 1) | 1) * 512 + lane * 8];
                int pr = (ks << 3) + (q << 2);
                uint4 wg4, wu4; u32* wgp = &wg4.x; u32* wup = &wu4.x;
                #pragma unroll
                for (int i = 0; i < 4; ++i) {
                    float2 pg = ptab[gcode[b][(pr + i) * 64 + cw] & 255];
                    float2 pu = ptab[ucode[b][(pr + i) * 64 + cw] & 255];
                    wgp[i] = bfpack2(pg.x * scg, pg.y * scg);
                    wup[i] = bfpack2(pu.x * scu, pu.y * scu);
                }
                bf16x8 bg = asbf(wg4), bu = asbf(wu4);
                accg[0] = MFMA32(a0, bg, accg[0], 0, 0, 0);
                accg[1] = MFMA32(a1, bg, accg[1], 0, 0, 0);
                accu[0] = MFMA32(a0, bu, accu[0], 0, 0, 0);
                accu[1] = MFMA32(a1, bu, accu[1], 0, 0, 0);
            }
        }

        // LoRA extension: += (x.A) . B  (K = 16)
        int r0 = s0 + (lane & 31), r1 = r0 + 32;
        {
            bf16x8 z = bfzero();
            bf16x8 ag0 = (r0 < cnt) ? *(const bf16x8*)(xAg + (size_t)(off + r0) * NR + q * 8) : z;
            bf16x8 ag1 = (r1 < cnt) ? *(const bf16x8*)(xAg + (size_t)(off + r1) * NR + q * 8) : z;
            bf16x8 au0 = (r0 < cnt) ? *(const bf16x8*)(xAu + (size_t)(off + r0) * NR + q * 8) : z;
            bf16x8 au1 = (r1 < cnt) ? *(const bf16x8*)(xAu + (size_t)(off + r1) * NR + q * 8) : z;
            const float* gq = gB + ((size_t)e * NR + q * 8) * NI + colg;
            const float* uq = uB + ((size_t)e * NR + q * 8) * NI + colg;
            uint4 wg4, wu4; u32* wgp = &wg4.x; u32* wup = &wu4.x;
            #pragma unroll
            for (int i = 0; i < 4; ++i) {
                wgp[i] = bfpack2(gq[(2 * i) * NI], gq[(2 * i + 1) * NI]);
                wup[i] = bfpack2(uq[(2 * i) * NI], uq[(2 * i + 1) * NI]);
            }
            bf16x8 bg = asbf(wg4), bu = asbf(wu4);
            accg[0] = MFMA32(ag0, bg, accg[0], 0, 0, 0);
            accg[1] = MFMA32(ag1, bg, accg[1], 0, 0, 0);
            accu[0] = MFMA32(au0, bu, accu[0], 0, 0, 0);
            accu[1] = MFMA32(au1, bu, accu[1], 0, 0, 0);
        }
        // epilogue: SiLU(g)*u -> hbuf (bf16)
        int rb = 4 * q;
        #pragma unroll
        for (int mi = 0; mi < 2; ++mi)
            #pragma unroll
            for (int reg = 0; reg < 16; ++reg) {
                int rloc = mi * 32 + rb + (reg & 3) + 8 * (reg >> 2);
                if (s0 + rloc < cnt) {
                    float g = accg[mi][reg], u = accu[mi][reg];
                    float h = g * u / (1.f + __expf(-g));
                    hbuf[(size_t)(off + s0 + rloc) * NI + colg] = (unsigned short)f2bf(h);
                }
            }
        __syncthreads();   // protect rowoff/bufs before next tile
    }
}

// -------- kernel 5: hA[p][r] = h . down_A (bf16 h in, bf16 out) --------
__global__ __launch_bounds__(256) void k_hA(const unsigned short* __restrict__ hbuf,
                                            const float* __restrict__ dA,
                                            const int* __restrict__ pexp,
                                            unsigned short* __restrict__ hA) {
    int p = blockIdx.x;
    int e = pexp[p];
    int tid = threadIdx.x;
    int r = tid & 15, ch = tid >> 4;   // 16 chunks of 64
    const unsigned short* hr = hbuf + (size_t)p * NI;
    const float* dAr = dA + (size_t)e * NI * NR;
    float sv = 0.f;
    for (int j = ch * 64; j < ch * 64 + 64; ++j) {
        float hv = __uint_as_float((u32)hr[j] << 16);
        sv += hv * dAr[j * NR + r];
    }
    __shared__ float red[16][16];
    red[ch][r] = sv;
    __syncthreads();
    for (int st = 8; st >= 1; st >>= 1) {
        if (ch < st) red[ch][r] += red[ch + st][r];
        __syncthreads();
    }
    if (tid < 16) hA[p * NR + tid] = (unsigned short)f2bf(red[0][tid]);
}

// -------- kernel 6: down GEMM, m97-style staging + routed atomic combine -----
__global__ __launch_bounds__(128) void k_down_mfma(
    const unsigned short* __restrict__ hbuf,
    const int* __restrict__ dpk, const float* __restrict__ dsc,
    const float* __restrict__ dB,
    const unsigned short* __restrict__ hA,
    const int* __restrict__ expert_off, const int* __restrict__ ptok,
    const float* __restrict__ pw,
    float* __restrict__ out)
{
    __shared__ float2 ptab[256];
    __shared__ u32 rowoff[64];
    __shared__ unsigned short afrag[2][4096];
    __shared__ u32 dcode[2][2048];
    __shared__ float dscl[2][64];

    int tid = threadIdx.x;
    int lane = tid & 63;
    int w = tid >> 6;
    int q = lane >> 5;
    for (int i = tid; i < 256; i += 128)
        ptab[i] = make_float2(NF4_TAB[i & 15], NF4_TAB[(i >> 4) & 15]);

    int e = blockIdx.x;
    int c0 = blockIdx.y * 64;
    int off = expert_off[e];
    int cnt = expert_off[e + 1] - off;
    int cw = (w << 5) | (lane & 31);
    int colg = c0 + cw;

    const u32* dpk_u = (const u32*)dpk;
    const size_t pkb = (size_t)e * (NI / 2) * NH;
    const size_t scb = (size_t)e * (NI / NGROUP) * NH;

    __syncthreads();

    for (int s0 = blockIdx.z * 64; s0 < cnt; s0 += 128) {
        if (tid < 64) {
            int rid = s0 + tid; if (rid > cnt - 1) rid = cnt - 1;
            rowoff[tid] = (u32)(off + rid) * (u32)NI;
        }
        __syncthreads();
        u32 ro0 = rowoff[lane & 31];
        u32 ro1 = rowoff[32 + (lane & 31)];

        f32x16 acc[2];
        #pragma unroll
        for (int i = 0; i < 16; ++i) { acc[0][i] = 0.f; acc[1][i] = 0.f; }

        auto stage = [&](int b, int k0) {
            int kp0 = k0 >> 1;
            for (int g = w; g < 8; g += 2) {
                int slot = (g << 6) | lane;
                int row = slot >> 4, cc = (slot & 15) << 2;
                stage16(dpk_u + pkb + (size_t)(kp0 + row) * NH + c0 + cc,
                        &dcode[b][g << 8]);
            }
            for (int fg = w; fg < 8; fg += 2) {
                int ks = fg >> 1, mi = fg & 1;
                u32 ro = mi ? ro1 : ro0;
                stage16(hbuf + ro + k0 + (ks << 4) + ((lane >> 5) << 3),
                        &afrag[b][fg << 9]);
            }
            if (w == 0)
                stage4(dsc + scb + (size_t)(k0 >> 6) * NH + c0 + lane, &dscl[b][0]);
        };

        stage(0, 0);
        for (int s = 0; s < NI / 64; ++s) {
            __syncthreads();
            if (s + 1 < NI / 64) stage((s + 1) & 1, (s + 1) * 64);
            int b = s & 1;
            float sc = dscl[b][cw];
            #pragma unroll
            for (int ks = 0; ks < 4; ++ks) {
                bf16x8 a0 = *(const bf16x8*)&afrag[b][((ks << 1) | 0) * 512 + lane * 8];
                bf16x8 a1 = *(const bf16x8*)&afrag[b][((ks << 1) | 1) * 512 + lane * 8];
                int pr = (ks << 3) + (q << 2);
                uint4 w4; u32* wp = &w4.x;
                #pragma unroll
                for (int i = 0; i < 4; ++i) {
                    float2 pv = ptab[dcode[b][(pr + i) * 64 + cw] & 255];
                    wp[i] = bfpack2(pv.x * sc, pv.y * sc);
                }
                bf16x8 bb = asbf(w4);
                acc[0] = MFMA32(a0, bb, acc[0], 0, 0, 0);
                acc[1] = MFMA32(a1, bb, acc[1], 0, 0, 0);
            }
        }

        // LoRA extension: += (h.down_A) . down_B (K = 16)
        int r0 = s0 + (lane & 31), r1 = r0 + 32;
        {
            bf16x8 z = bfzero();
            bf16x8 a0 = (r0 < cnt) ? *(const bf16x8*)(hA + (size_t)(off + r0) * NR + q * 8) : z;
            bf16x8 a1 = (r1 < cnt) ? *(const bf16x8*)(hA + (size_t)(off + r1) * NR + q * 8) : z;
            const float* dq_ = dB + ((size_t)e * NR + q * 8) * NH + colg;
            uint4 w4; u32* wp = &w4.x;
            #pragma unroll
            for (int i = 0; i < 4; ++i)
                wp[i] = bfpack2(dq_[(2 * i) * NH], dq_[(2 * i + 1) * NH]);
            bf16x8 bb = asbf(w4);
            acc[0] = MFMA32(a0, bb, acc[0], 0, 0, 0);
            acc[1] = MFMA32(a1, bb, acc[1], 0, 0, 0);
        }
        // epilogue: weighted atomic combine into out
        int rb = 4 * q;
        #pragma unroll
        for (int mi = 0; mi < 2; ++mi)
            #pragma unroll
            for (int reg = 0; reg < 16; ++reg) {
                int rloc = mi * 32 + rb + (reg & 3) + 8 * (reg >> 2);
                if (s0 + rloc < cnt) {
                    int p = off + s0 + rloc;
                    float v = acc[mi][reg] * pw[p];
                    atomicAdd(&out[(size_t)ptok[p] * NH + colg], v);
                }
            }
        __syncthreads();
    }
}

extern "C" void kernel_launch(void* const* d_in, const int* in_sizes, int n_in,
                              void* d_out, int out_size, void* d_ws,
                              size_t ws_size, hipStream_t stream) {
    const float* x = (const float*)d_in[0];
    const int* topk_idx = (const int*)d_in[1];
    const float* topk_w = (const float*)d_in[2];
    const int* gate_packed = (const int*)d_in[3];
    const float* gate_scales = (const float*)d_in[4];
    const int* up_packed = (const int*)d_in[5];
    const float* up_scales = (const float*)d_in[6];
    const int* down_packed = (const int*)d_in[7];
    const float* down_scales = (const float*)d_in[8];
    const float* gate_A = (const float*)d_in[9];
    const float* gate_B = (const float*)d_in[10];
    const float* up_A = (const float*)d_in[11];
    const float* up_B = (const float*)d_in[12];
    const float* down_A = (const float*)d_in[13];
    const float* down_B = (const float*)d_in[14];
    float* out = (float*)d_out;

    char* ws = (char*)d_ws;
    int* expert_off = (int*)(ws + OFF_EXPOFF);
    int* ptok = (int*)(ws + OFF_TOK);
    int* pexp = (int*)(ws + OFF_EXP);
    float* pw = (float*)(ws + OFF_W);
    unsigned short* xAg = (unsigned short*)(ws + OFF_XAG);
    unsigned short* xAu = (unsigned short*)(ws + OFF_XAU);
    unsigned short* hA = (unsigned short*)(ws + OFF_HA);
    unsigned short* xb = (unsigned short*)(ws + OFF_XB);
    unsigned short* hbuf = (unsigned short*)(ws + OFF_HBUF);

    hipMemsetAsync(d_out, 0, (size_t)NT * NH * sizeof(float), stream);

    k_route<<<1, 1024, 0, stream>>>(topk_idx, topk_w, expert_off, ptok, pexp, pw);
    k_xcvt<<<(NT * NH) / (256 * 8), 256, 0, stream>>>(x, xb);
    k_xA<<<NPAIR, 256, 0, stream>>>(x, gate_A, up_A, ptok, pexp, xAg, xAu);
    k_gateup_mfma<<<dim3(NE, NI / 64, 2), 128, 0, stream>>>(
        xb, gate_packed, gate_scales, up_packed, up_scales, gate_B, up_B,
        xAg, xAu, expert_off, ptok, hbuf);
    k_hA<<<NPAIR, 256, 0, stream>>>(hbuf, down_A, pexp, hA);
    k_down_mfma<<<dim3(NE, NH / 64, 2), 128, 0, stream>>>(
        hbuf, down_packed, down_scales, down_B, hA, expert_off, ptok, pw, out);
}

// Round 5
// 342.617 us; speedup vs baseline: 1.0273x; 1.0273x over previous
//
#include <hip/hip_runtime.h>
#include <math.h>

#define NE 8
#define NH 2048
#define NI 1024
#define NT 512
#define NTOPK 2
#define NR 16
#define NGROUP 64
#define NPAIR (NT*NTOPK)   // 1024

typedef short bf16x8 __attribute__((ext_vector_type(8)));
typedef float f32x16 __attribute__((ext_vector_type(16)));
typedef unsigned int u32;

#define MFMA32 __builtin_amdgcn_mfma_f32_32x32x16_bf16

__device__ const float NF4_TAB[16] = {
    -1.0f, -0.6961928009986877f, -0.5250730514526367f, -0.39491748809814453f,
    -0.28444138169288635f, -0.18477343022823334f, -0.09105003625154495f, 0.0f,
    0.07958029955625534f, 0.16093020141124725f, 0.24611230194568634f,
    0.33791524171829224f, 0.44070982933044434f, 0.5626170039176941f,
    0.7229568362236328f, 1.0f};

// ---------------- workspace layout (bytes) ----------------
#define OFF_EXPOFF 0         // int[16]
#define OFF_TOK    256       // int[1024]
#define OFF_EXP    4352      // int[1024]
#define OFF_W      8448      // float[1024]
#define OFF_XAG    12544     // ushort[1024*16] bf16
#define OFF_XAU    45312     // ushort[1024*16]
#define OFF_HA     78080     // ushort[1024*16]
#define OFF_XB     131072    // ushort[512*2048] bf16 x (2 MB)
#define OFF_GU     2228224   // ushort[2*1024*1024] gate|up results (4 MB)
#define OFF_HBUF   6422528   // ushort[1024*1024] bf16 h (2 MB)

__device__ inline u32 f2bf(float f) {
    return (__float_as_uint(f) + 0x8000u) >> 16;
}
__device__ inline u32 bfpack2(float a, float b) {
    return ((__float_as_uint(a) + 0x8000u) >> 16) |
           ((__float_as_uint(b) + 0x8000u) & 0xFFFF0000u);
}
__device__ inline bf16x8 asbf(uint4 w) {
    union { uint4 u; bf16x8 b; } c; c.u = w; return c.b;
}
__device__ inline bf16x8 bfzero() { return asbf(make_uint4(0,0,0,0)); }
__device__ inline float bf2f(u32 v) { return __uint_as_float(v << 16); }

// async global->LDS: per-lane global addr, LDS dest = wave-uniform base + lane*16
__device__ __forceinline__ void stage16(const void* g, void* l) {
    __builtin_amdgcn_global_load_lds(
        (const __attribute__((address_space(1))) u32*)g,
        (__attribute__((address_space(3))) u32*)l, 16, 0, 0);
}

// -------- kernel 1: routing compaction --------
__global__ __launch_bounds__(1024) void k_route(const int* __restrict__ idx,
                                                const float* __restrict__ w,
                                                int* expert_off, int* ptok,
                                                int* pexp, float* pw) {
    __shared__ int cnt[NE], off[NE + 1], cur[NE];
    int tid = threadIdx.x;
    if (tid < NE) cnt[tid] = 0;
    __syncthreads();
    int e = idx[tid];
    float wt = w[tid];
    int t = tid >> 1;
    atomicAdd(&cnt[e], 1);
    __syncthreads();
    if (tid == 0) {
        off[0] = 0;
        for (int i = 0; i < NE; i++) off[i + 1] = off[i] + cnt[i];
    }
    __syncthreads();
    if (tid < NE) cur[tid] = off[tid];
    __syncthreads();
    int pos = atomicAdd(&cur[e], 1);
    ptok[pos] = t; pexp[pos] = e; pw[pos] = wt;
    if (tid <= NE) expert_off[tid] = off[tid];
}

// -------- kernel 2: x fp32 -> bf16 --------
__global__ __launch_bounds__(256) void k_xcvt(const float* __restrict__ x,
                                              unsigned short* __restrict__ xb) {
    int i = (blockIdx.x * 256 + threadIdx.x) * 8;
    float4 v0 = *(const float4*)(x + i);
    float4 v1 = *(const float4*)(x + i + 4);
    uint4 w;
    w.x = bfpack2(v0.x, v0.y); w.y = bfpack2(v0.z, v0.w);
    w.z = bfpack2(v1.x, v1.y); w.w = bfpack2(v1.z, v1.w);
    *(uint4*)(xb + i) = w;
}

// -------- kernel 3: xA_g[p][r], xA_u[p][r] --------
__global__ __launch_bounds__(256) void k_xA(const float* __restrict__ x,
                                            const float* __restrict__ gA,
                                            const float* __restrict__ uA,
                                            const int* __restrict__ ptok,
                                            const int* __restrict__ pexp,
                                            unsigned short* __restrict__ xAg,
                                            unsigned short* __restrict__ xAu) {
    int p = blockIdx.x;
    int t = ptok[p], e = pexp[p];
    int tid = threadIdx.x;
    int r = tid & 15, ch = tid >> 4;
    const float* xr = x + (size_t)t * NH;
    const float* gAr = gA + (size_t)e * NH * NR;
    const float* uAr = uA + (size_t)e * NH * NR;
    float sg = 0.f, su = 0.f;
    for (int j = ch * 128; j < ch * 128 + 128; ++j) {
        float xv = xr[j];
        sg += xv * gAr[j * NR + r];
        su += xv * uAr[j * NR + r];
    }
    __shared__ float red[2][16][16];
    red[0][ch][r] = sg; red[1][ch][r] = su;
    __syncthreads();
    for (int st = 8; st >= 1; st >>= 1) {
        if (ch < st) {
            red[0][ch][r] += red[0][ch + st][r];
            red[1][ch][r] += red[1][ch + st][r];
        }
        __syncthreads();
    }
    if (tid < 16) {
        xAg[p * NR + tid] = (unsigned short)f2bf(red[0][0][tid]);
        xAu[p * NR + tid] = (unsigned short)f2bf(red[1][0][tid]);
    }
}

// -------- kernel 4: gate OR up grouped GEMM (1 wave/block, DMA staging) ------
// tile: 64 rows x 32 cols, one matrix (blockIdx.z&1). Per-step unscaled MFMA
// into temp acc, then main += scale*temp (NGROUP == K-step == 64).
__global__ __launch_bounds__(64) void k_gu(
    const unsigned short* __restrict__ xb,
    const int* __restrict__ gpk, const float* __restrict__ gsc,
    const int* __restrict__ upk, const float* __restrict__ usc,
    const float* __restrict__ gB, const float* __restrict__ uB,
    const unsigned short* __restrict__ xAg, const unsigned short* __restrict__ xAu,
    const int* __restrict__ expert_off, const int* __restrict__ ptok,
    unsigned short* __restrict__ gu)
{
    __shared__ u32 lut[256];                  // packed bf16-pair codes, 1 KB
    __shared__ u32 code[2][1024];             // [prow 0..31][col 0..31], 2x4 KB
    __shared__ unsigned short afrag[2][4096]; // A frags, 2x8 KB

    int lane = threadIdx.x;
    int q = lane >> 5;
    for (int i = lane; i < 256; i += 64)
        lut[i] = bfpack2(NF4_TAB[i & 15], NF4_TAB[(i >> 4) & 15]);

    int e = blockIdx.x;
    int c0 = blockIdx.y * 32;
    int mat = blockIdx.z & 1;
    int zz = blockIdx.z >> 1;
    const u32* pk = (const u32*)(mat ? upk : gpk);
    const float* scp = mat ? usc : gsc;
    const float* Bp = mat ? uB : gB;
    const unsigned short* xA = mat ? xAu : xAg;

    int off = expert_off[e];
    int cnt = expert_off[e + 1] - off;
    int cw = lane & 31;
    int colg = c0 + cw;

    const size_t pkb = (size_t)e * (NH / 2) * NI;
    const float* scl_base = scp + (size_t)e * (NH / NGROUP) * NI + colg;

    __syncthreads();

    for (int s0 = zz * 64; s0 < cnt; s0 += 128) {
        int rr0 = s0 + cw;      if (rr0 > cnt - 1) rr0 = cnt - 1;
        int rr1 = s0 + 32 + cw; if (rr1 > cnt - 1) rr1 = cnt - 1;
        u32 ro0 = (u32)ptok[off + rr0] * (u32)NH;
        u32 ro1 = (u32)ptok[off + rr1] * (u32)NH;

        f32x16 main0, main1;
        #pragma unroll
        for (int i = 0; i < 16; ++i) { main0[i] = 0.f; main1[i] = 0.f; }

        auto stage = [&](int b, int k0) {
            int kp0 = k0 >> 1;
            #pragma unroll
            for (int g = 0; g < 4; ++g)
                stage16(pk + pkb + (size_t)(kp0 + (g << 3) + (lane >> 3)) * NI
                            + c0 + ((lane & 7) << 2),
                        &code[b][g << 8]);
            #pragma unroll
            for (int ks = 0; ks < 4; ++ks) {
                stage16(xb + ro0 + k0 + (ks << 4) + (q << 3),
                        &afrag[b][(ks * 2 + 0) << 9]);
                stage16(xb + ro1 + k0 + (ks << 4) + (q << 3),
                        &afrag[b][(ks * 2 + 1) << 9]);
            }
        };

        stage(0, 0);
        float scl_cur = scl_base[0];
        const int NS = NH / 64;              // 32 steps
        for (int s = 0; s < NS; ++s) {
            float scl_nxt = (s + 1 < NS) ? scl_base[(size_t)(s + 1) * NI] : 0.f;
            __syncthreads();                 // drain stage(s)
            if (s + 1 < NS) stage((s + 1) & 1, (s + 1) * 64);
            int b = s & 1;
            f32x16 t0, t1;
            #pragma unroll
            for (int i = 0; i < 16; ++i) { t0[i] = 0.f; t1[i] = 0.f; }
            #pragma unroll
            for (int ks = 0; ks < 4; ++ks) {
                bf16x8 a0 = *(const bf16x8*)&afrag[b][((ks * 2 + 0) << 9) + (lane << 3)];
                bf16x8 a1 = *(const bf16x8*)&afrag[b][((ks * 2 + 1) << 9) + (lane << 3)];
                int pr = (ks << 3) + (q << 2);
                uint4 w4; u32* wp = &w4.x;
                #pragma unroll
                for (int i = 0; i < 4; ++i)
                    wp[i] = lut[code[b][((pr + i) << 5) + cw] & 255];
                bf16x8 bb = asbf(w4);
                t0 = MFMA32(a0, bb, t0, 0, 0, 0);
                t1 = MFMA32(a1, bb, t1, 0, 0, 0);
            }
            #pragma unroll
            for (int i = 0; i < 16; ++i) {
                main0[i] += scl_cur * t0[i];
                main1[i] += scl_cur * t1[i];
            }
            scl_cur = scl_nxt;
        }

        // LoRA extension: += (x.A) . B  (K = 16)
        {
            bf16x8 z = bfzero();
            bf16x8 la0 = (s0 + cw < cnt)
                ? *(const bf16x8*)(xA + (size_t)(off + s0 + cw) * NR + q * 8) : z;
            bf16x8 la1 = (s0 + 32 + cw < cnt)
                ? *(const bf16x8*)(xA + (size_t)(off + s0 + 32 + cw) * NR + q * 8) : z;
            const float* Bq = Bp + ((size_t)e * NR + q * 8) * NI + colg;
            uint4 w4; u32* wp = &w4.x;
            #pragma unroll
            for (int i = 0; i < 4; ++i)
                wp[i] = bfpack2(Bq[(2 * i) * NI], Bq[(2 * i + 1) * NI]);
            bf16x8 bb = asbf(w4);
            main0 = MFMA32(la0, bb, main0, 0, 0, 0);
            main1 = MFMA32(la1, bb, main1, 0, 0, 0);
        }
        // epilogue: store bf16 result tile
        unsigned short* outb = gu + (size_t)mat * NPAIR * NI;
        int rb = q * 4;
        #pragma unroll
        for (int mi = 0; mi < 2; ++mi) {
            const f32x16& m = mi ? main1 : main0;
            #pragma unroll
            for (int reg = 0; reg < 16; ++reg) {
                int rloc = mi * 32 + rb + (reg & 3) + 8 * (reg >> 2);
                if (s0 + rloc < cnt)
                    outb[(size_t)(off + s0 + rloc) * NI + colg] =
                        (unsigned short)f2bf(m[reg]);
            }
        }
    }
}

// -------- kernel 5: h = silu(gate)*up --------
__global__ __launch_bounds__(256) void k_swiglu(const unsigned short* __restrict__ gu,
                                                unsigned short* __restrict__ hbuf) {
    int i = (blockIdx.x * 256 + threadIdx.x) * 8;
    uint4 gv = *(const uint4*)(gu + i);
    uint4 uv = *(const uint4*)(gu + (size_t)NPAIR * NI + i);
    const u32* gp = &gv.x; const u32* up = &uv.x;
    uint4 hv; u32* hp = &hv.x;
    #pragma unroll
    for (int j = 0; j < 4; ++j) {
        float g0 = bf2f(gp[j] & 0xFFFFu), g1 = bf2f(gp[j] >> 16);
        float u0 = bf2f(up[j] & 0xFFFFu), u1 = bf2f(up[j] >> 16);
        float h0 = g0 * u0 / (1.f + __expf(-g0));
        float h1 = g1 * u1 / (1.f + __expf(-g1));
        hp[j] = bfpack2(h0, h1);
    }
    *(uint4*)(hbuf + i) = hv;
}

// -------- kernel 6: hA[p][r] = h . down_A --------
__global__ __launch_bounds__(256) void k_hA(const unsigned short* __restrict__ hbuf,
                                            const float* __restrict__ dA,
                                            const int* __restrict__ pexp,
                                            unsigned short* __restrict__ hA) {
    int p = blockIdx.x;
    int e = pexp[p];
    int tid = threadIdx.x;
    int r = tid & 15, ch = tid >> 4;
    const unsigned short* hr = hbuf + (size_t)p * NI;
    const float* dAr = dA + (size_t)e * NI * NR;
    float sv = 0.f;
    for (int j = ch * 64; j < ch * 64 + 64; ++j) {
        float hv = bf2f(hr[j]);
        sv += hv * dAr[j * NR + r];
    }
    __shared__ float red[16][16];
    red[ch][r] = sv;
    __syncthreads();
    for (int st = 8; st >= 1; st >>= 1) {
        if (ch < st) red[ch][r] += red[ch + st][r];
        __syncthreads();
    }
    if (tid < 16) hA[p * NR + tid] = (unsigned short)f2bf(red[0][tid]);
}

// -------- kernel 7: down GEMM (1 wave/block, DMA staging) + combine ----------
__global__ __launch_bounds__(64) void k_dn(
    const unsigned short* __restrict__ hbuf,
    const int* __restrict__ dpk, const float* __restrict__ dsc,
    const float* __restrict__ dB,
    const unsigned short* __restrict__ hA,
    const int* __restrict__ expert_off, const int* __restrict__ ptok,
    const float* __restrict__ pw,
    float* __restrict__ out)
{
    __shared__ u32 lut[256];
    __shared__ u32 code[2][1024];
    __shared__ unsigned short afrag[2][4096];

    int lane = threadIdx.x;
    int q = lane >> 5;
    for (int i = lane; i < 256; i += 64)
        lut[i] = bfpack2(NF4_TAB[i & 15], NF4_TAB[(i >> 4) & 15]);

    int e = blockIdx.x;
    int c0 = blockIdx.y * 32;
    int zz = blockIdx.z;
    const u32* pk = (const u32*)dpk;

    int off = expert_off[e];
    int cnt = expert_off[e + 1] - off;
    int cw = lane & 31;
    int colg = c0 + cw;

    const size_t pkb = (size_t)e * (NI / 2) * NH;
    const float* scl_base = dsc + (size_t)e * (NI / NGROUP) * NH + colg;

    __syncthreads();

    for (int s0 = zz * 64; s0 < cnt; s0 += 128) {
        int rr0 = s0 + cw;      if (rr0 > cnt - 1) rr0 = cnt - 1;
        int rr1 = s0 + 32 + cw; if (rr1 > cnt - 1) rr1 = cnt - 1;
        u32 ro0 = (u32)(off + rr0) * (u32)NI;
        u32 ro1 = (u32)(off + rr1) * (u32)NI;

        f32x16 main0, main1;
        #pragma unroll
        for (int i = 0; i < 16; ++i) { main0[i] = 0.f; main1[i] = 0.f; }

        auto stage = [&](int b, int k0) {
            int kp0 = k0 >> 1;
            #pragma unroll
            for (int g = 0; g < 4; ++g)
                stage16(pk + pkb + (size_t)(kp0 + (g << 3) + (lane >> 3)) * NH
                            + c0 + ((lane & 7) << 2),
                        &code[b][g << 8]);
            #pragma unroll
            for (int ks = 0; ks < 4; ++ks) {
                stage16(hbuf + ro0 + k0 + (ks << 4) + (q << 3),
                        &afrag[b][(ks * 2 + 0) << 9]);
                stage16(hbuf + ro1 + k0 + (ks << 4) + (q << 3),
                        &afrag[b][(ks * 2 + 1) << 9]);
            }
        };

        stage(0, 0);
        float scl_cur = scl_base[0];
        const int NS = NI / 64;              // 16 steps
        for (int s = 0; s < NS; ++s) {
            float scl_nxt = (s + 1 < NS) ? scl_base[(size_t)(s + 1) * NH] : 0.f;
            __syncthreads();
            if (s + 1 < NS) stage((s + 1) & 1, (s + 1) * 64);
            int b = s & 1;
            f32x16 t0, t1;
            #pragma unroll
            for (int i = 0; i < 16; ++i) { t0[i] = 0.f; t1[i] = 0.f; }
            #pragma unroll
            for (int ks = 0; ks < 4; ++ks) {
                bf16x8 a0 = *(const bf16x8*)&afrag[b][((ks * 2 + 0) << 9) + (lane << 3)];
                bf16x8 a1 = *(const bf16x8*)&afrag[b][((ks * 2 + 1) << 9) + (lane << 3)];
                int pr = (ks << 3) + (q << 2);
                uint4 w4; u32* wp = &w4.x;
                #pragma unroll
                for (int i = 0; i < 4; ++i)
                    wp[i] = lut[code[b][((pr + i) << 5) + cw] & 255];
                bf16x8 bb = asbf(w4);
                t0 = MFMA32(a0, bb, t0, 0, 0, 0);
                t1 = MFMA32(a1, bb, t1, 0, 0, 0);
            }
            #pragma unroll
            for (int i = 0; i < 16; ++i) {
                main0[i] += scl_cur * t0[i];
                main1[i] += scl_cur * t1[i];
            }
            scl_cur = scl_nxt;
        }

        // LoRA extension: += (h.down_A) . down_B (K = 16)
        {
            bf16x8 z = bfzero();
            bf16x8 la0 = (s0 + cw < cnt)
                ? *(const bf16x8*)(hA + (size_t)(off + s0 + cw) * NR + q * 8) : z;
            bf16x8 la1 = (s0 + 32 + cw < cnt)
                ? *(const bf16x8*)(hA + (size_t)(off + s0 + 32 + cw) * NR + q * 8) : z;
            const float* Bq = dB + ((size_t)e * NR + q * 8) * NH + colg;
            uint4 w4; u32* wp = &w4.x;
            #pragma unroll
            for (int i = 0; i < 4; ++i)
                wp[i] = bfpack2(Bq[(2 * i) * NH], Bq[(2 * i + 1) * NH]);
            bf16x8 bb = asbf(w4);
            main0 = MFMA32(la0, bb, main0, 0, 0, 0);
            main1 = MFMA32(la1, bb, main1, 0, 0, 0);
        }
        // epilogue: weighted atomic combine
        int rb = q * 4;
        #pragma unroll
        for (int mi = 0; mi < 2; ++mi) {
            const f32x16& m = mi ? main1 : main0;
            #pragma unroll
            for (int reg = 0; reg < 16; ++reg) {
                int rloc = mi * 32 + rb + (reg & 3) + 8 * (reg >> 2);
                if (s0 + rloc < cnt) {
                    int p = off + s0 + rloc;
                    atomicAdd(&out[(size_t)ptok[p] * NH + colg], m[reg] * pw[p]);
                }
            }
        }
    }
}

extern "C" void kernel_launch(void* const* d_in, const int* in_sizes, int n_in,
                              void* d_out, int out_size, void* d_ws,
                              size_t ws_size, hipStream_t stream) {
    const float* x = (const float*)d_in[0];
    const int* topk_idx = (const int*)d_in[1];
    const float* topk_w = (const float*)d_in[2];
    const int* gate_packed = (const int*)d_in[3];
    const float* gate_scales = (const float*)d_in[4];
    const int* up_packed = (const int*)d_in[5];
    const float* up_scales = (const float*)d_in[6];
    const int* down_packed = (const int*)d_in[7];
    const float* down_scales = (const float*)d_in[8];
    const float* gate_A = (const float*)d_in[9];
    const float* gate_B = (const float*)d_in[10];
    const float* up_A = (const float*)d_in[11];
    const float* up_B = (const float*)d_in[12];
    const float* down_A = (const float*)d_in[13];
    const float* down_B = (const float*)d_in[14];
    float* out = (float*)d_out;

    char* ws = (char*)d_ws;
    int* expert_off = (int*)(ws + OFF_EXPOFF);
    int* ptok = (int*)(ws + OFF_TOK);
    int* pexp = (int*)(ws + OFF_EXP);
    float* pw = (float*)(ws + OFF_W);
    unsigned short* xAg = (unsigned short*)(ws + OFF_XAG);
    unsigned short* xAu = (unsigned short*)(ws + OFF_XAU);
    unsigned short* hA = (unsigned short*)(ws + OFF_HA);
    unsigned short* xb = (unsigned short*)(ws + OFF_XB);
    unsigned short* gu = (unsigned short*)(ws + OFF_GU);
    unsigned short* hbuf = (unsigned short*)(ws + OFF_HBUF);

    hipMemsetAsync(d_out, 0, (size_t)NT * NH * sizeof(float), stream);

    k_route<<<1, 1024, 0, stream>>>(topk_idx, topk_w, expert_off, ptok, pexp, pw);
    k_xcvt<<<(NT * NH) / (256 * 8), 256, 0, stream>>>(x, xb);
    k_xA<<<NPAIR, 256, 0, stream>>>(x, gate_A, up_A, ptok, pexp, xAg, xAu);
    k_gu<<<dim3(NE, NI / 32, 4), 64, 0, stream>>>(
        xb, gate_packed, gate_scales, up_packed, up_scales, gate_B, up_B,
        xAg, xAu, expert_off, ptok, gu);
    k_swiglu<<<(NPAIR * NI) / (256 * 8), 256, 0, stream>>>(gu, hbuf);
    k_hA<<<NPAIR, 256, 0, stream>>>(hbuf, down_A, pexp, hA);
    k_dn<<<dim3(NE, NH / 32, 2), 64, 0, stream>>>(
        hbuf, down_packed, down_scales, down_B, hA, expert_off, ptok, pw, out);
}

// Round 6
// 293.489 us; speedup vs baseline: 1.1993x; 1.1674x over previous
//
#include <hip/hip_runtime.h>
#include <math.h>

#define NE 8
#define NH 2048
#define NI 1024
#define NT 512
#define NTOPK 2
#define NR 16
#define NGROUP 64
#define NPAIR (NT*NTOPK)   // 1024

typedef short bf16x8 __attribute__((ext_vector_type(8)));
typedef float f32x16 __attribute__((ext_vector_type(16)));
typedef unsigned int u32;

#define MFMA32 __builtin_amdgcn_mfma_f32_32x32x16_bf16

__device__ const float NF4_TAB[16] = {
    -1.0f, -0.6961928009986877f, -0.5250730514526367f, -0.39491748809814453f,
    -0.28444138169288635f, -0.18477343022823334f, -0.09105003625154495f, 0.0f,
    0.07958029955625534f, 0.16093020141124725f, 0.24611230194568634f,
    0.33791524171829224f, 0.44070982933044434f, 0.5626170039176941f,
    0.7229568362236328f, 1.0f};

// ---------------- workspace layout (bytes) ----------------
#define OFF_EXPOFF 0         // int[16]
#define OFF_TOK    256       // int[1024]
#define OFF_EXP    4352      // int[1024]
#define OFF_W      8448      // float[1024]
#define OFF_XAG    12544     // ushort[1024*16] bf16
#define OFF_XAU    45312     // ushort[1024*16]
#define OFF_HA     78080     // ushort[1024*16]
#define OFF_XB     131072    // ushort[512*2048] bf16 x (2 MB)
#define OFF_GU     2228224   // ushort[2*1024*1024] gate|up results (4 MB)
#define OFF_HBUF   6422528   // ushort[1024*1024] bf16 h (2 MB)

__device__ inline u32 f2bf(float f) {
    return (__float_as_uint(f) + 0x8000u) >> 16;
}
__device__ inline u32 bfpack2(float a, float b) {
    return ((__float_as_uint(a) + 0x8000u) >> 16) |
           ((__float_as_uint(b) + 0x8000u) & 0xFFFF0000u);
}
__device__ inline bf16x8 asbf(uint4 w) {
    union { uint4 u; bf16x8 b; } c; c.u = w; return c.b;
}
__device__ inline bf16x8 bfzero() { return asbf(make_uint4(0,0,0,0)); }
__device__ inline float bf2f(u32 v) { return __uint_as_float(v << 16); }

// async global->LDS: per-lane global addr, LDS dest = wave-uniform base + lane*16
__device__ __forceinline__ void stage16(const void* g, void* l) {
    __builtin_amdgcn_global_load_lds(
        (const __attribute__((address_space(1))) u32*)g,
        (__attribute__((address_space(3))) u32*)l, 16, 0, 0);
}

// single-wave pipeline waits (blocks are 1 wave: NO __syncthreads anywhere in
// the K-loop; vmcnt(8) = previous 8-instr stage landed, newest stage in flight)
#define WAIT_PREV_STAGE() asm volatile("s_waitcnt vmcnt(8)" ::: "memory")
#define WAIT_ALL()        asm volatile("s_waitcnt vmcnt(0)" ::: "memory")

// -------- kernel 1: routing compaction --------
__global__ __launch_bounds__(1024) void k_route(const int* __restrict__ idx,
                                                const float* __restrict__ w,
                                                int* expert_off, int* ptok,
                                                int* pexp, float* pw) {
    __shared__ int cnt[NE], off[NE + 1], cur[NE];
    int tid = threadIdx.x;
    if (tid < NE) cnt[tid] = 0;
    __syncthreads();
    int e = idx[tid];
    float wt = w[tid];
    int t = tid >> 1;
    atomicAdd(&cnt[e], 1);
    __syncthreads();
    if (tid == 0) {
        off[0] = 0;
        for (int i = 0; i < NE; i++) off[i + 1] = off[i] + cnt[i];
    }
    __syncthreads();
    if (tid < NE) cur[tid] = off[tid];
    __syncthreads();
    int pos = atomicAdd(&cur[e], 1);
    ptok[pos] = t; pexp[pos] = e; pw[pos] = wt;
    if (tid <= NE) expert_off[tid] = off[tid];
}

// -------- kernel 2: x fp32 -> bf16 --------
__global__ __launch_bounds__(256) void k_xcvt(const float* __restrict__ x,
                                              unsigned short* __restrict__ xb) {
    int i = (blockIdx.x * 256 + threadIdx.x) * 8;
    float4 v0 = *(const float4*)(x + i);
    float4 v1 = *(const float4*)(x + i + 4);
    uint4 w;
    w.x = bfpack2(v0.x, v0.y); w.y = bfpack2(v0.z, v0.w);
    w.z = bfpack2(v1.x, v1.y); w.w = bfpack2(v1.z, v1.w);
    *(uint4*)(xb + i) = w;
}

// -------- kernel 3: xA_g[p][r], xA_u[p][r] --------
__global__ __launch_bounds__(256) void k_xA(const float* __restrict__ x,
                                            const float* __restrict__ gA,
                                            const float* __restrict__ uA,
                                            const int* __restrict__ ptok,
                                            const int* __restrict__ pexp,
                                            unsigned short* __restrict__ xAg,
                                            unsigned short* __restrict__ xAu) {
    int p = blockIdx.x;
    int t = ptok[p], e = pexp[p];
    int tid = threadIdx.x;
    int r = tid & 15, ch = tid >> 4;
    const float* xr = x + (size_t)t * NH;
    const float* gAr = gA + (size_t)e * NH * NR;
    const float* uAr = uA + (size_t)e * NH * NR;
    float sg = 0.f, su = 0.f;
    for (int j = ch * 128; j < ch * 128 + 128; ++j) {
        float xv = xr[j];
        sg += xv * gAr[j * NR + r];
        su += xv * uAr[j * NR + r];
    }
    __shared__ float red[2][16][16];
    red[0][ch][r] = sg; red[1][ch][r] = su;
    __syncthreads();
    for (int st = 8; st >= 1; st >>= 1) {
        if (ch < st) {
            red[0][ch][r] += red[0][ch + st][r];
            red[1][ch][r] += red[1][ch + st][r];
        }
        __syncthreads();
    }
    if (tid < 16) {
        xAg[p * NR + tid] = (unsigned short)f2bf(red[0][0][tid]);
        xAu[p * NR + tid] = (unsigned short)f2bf(red[1][0][tid]);
    }
}

// -------- kernel 4: gate OR up grouped GEMM --------
// 1 wave/block, tile 32 rows x 32 cols. 3 LDS buffers, 2 stages always in
// flight, vmcnt(8)-gated single-wave pipeline (no barriers).
__global__ __launch_bounds__(64) void k_gu(
    const unsigned short* __restrict__ xb,
    const int* __restrict__ gpk, const float* __restrict__ gsc,
    const int* __restrict__ upk, const float* __restrict__ usc,
    const float* __restrict__ gB, const float* __restrict__ uB,
    const unsigned short* __restrict__ xAg, const unsigned short* __restrict__ xAu,
    const int* __restrict__ expert_off, const int* __restrict__ ptok,
    unsigned short* __restrict__ gu)
{
    __shared__ u32 lut[256];                  // bf16-pair dequant LUT, 1 KB
    __shared__ u32 code[3][1024];             // 32 prows x 32 cols, 3x4 KB
    __shared__ unsigned short afrag[3][2048]; // 4 ks x 64 frag-slots, 3x4 KB
    __shared__ float sclb[32][32];            // [step][col], 4 KB

    int lane = threadIdx.x;
    int q = lane >> 5, cw = lane & 31;
    for (int i = lane; i < 256; i += 64)
        lut[i] = bfpack2(NF4_TAB[i & 15], NF4_TAB[(i >> 4) & 15]);

    int e = blockIdx.x;
    int c0 = blockIdx.y * 32;
    int mat = blockIdx.z & 1;
    int rt = blockIdx.z >> 1;                 // row-tile 0..3
    const u32* pk = (const u32*)(mat ? upk : gpk);
    const float* scp = mat ? usc : gsc;
    const float* Bp = mat ? uB : gB;
    const unsigned short* xA = mat ? xAu : xAg;

    int off = expert_off[e];
    int cnt = expert_off[e + 1] - off;
    int colg = c0 + cw;
    const size_t pkb = (size_t)e * (NH / 2) * NI;

    // stage all 32 per-step scales once per block: sclb[s][col]
    {
        const float* sg = scp + (size_t)e * (NH / NGROUP) * NI + c0;
        #pragma unroll
        for (int g = 0; g < 4; ++g)
            stage16(sg + (size_t)(g * 8 + (lane >> 3)) * NI + ((lane & 7) << 2),
                    &sclb[g * 8][0]);
    }

    const int NS = NH / 64;                   // 32 K-steps
    for (int s0 = rt * 32; s0 < cnt; s0 += 128) {
        int rr = s0 + cw; if (rr > cnt - 1) rr = cnt - 1;
        u32 ro = (u32)ptok[off + rr] * (u32)NH;   // lanes l and l+32 identical

        auto stage = [&](int b, int k0) {     // exactly 8 global_load_lds
            int kp0 = k0 >> 1;
            #pragma unroll
            for (int g = 0; g < 4; ++g)
                stage16(pk + pkb + (size_t)(kp0 + (g << 3) + (lane >> 3)) * NI
                            + c0 + ((lane & 7) << 2),
                        &code[b][g << 8]);
            #pragma unroll
            for (int ks = 0; ks < 4; ++ks)
                stage16(xb + ro + k0 + (ks << 4) + (q << 3),
                        &afrag[b][ks << 9]);
        };

        f32x16 acc;
        #pragma unroll
        for (int i = 0; i < 16; ++i) acc[i] = 0.f;

        stage(0, 0);
        stage(1, 64);
        for (int s = 0; s < NS; ++s) {
            if (s + 1 < NS) WAIT_PREV_STAGE(); else WAIT_ALL();
            if (s + 2 < NS) stage((s + 2) % 3, (s + 2) * 64);
            int b = s % 3;
            float scl = sclb[s][cw];
            f32x16 t;
            #pragma unroll
            for (int i = 0; i < 16; ++i) t[i] = 0.f;
            #pragma unroll
            for (int ks = 0; ks < 4; ++ks) {
                bf16x8 a = *(const bf16x8*)&afrag[b][(ks << 9) + (lane << 3)];
                uint4 w4; u32* wp = &w4.x;
                #pragma unroll
                for (int i = 0; i < 4; ++i)
                    wp[i] = lut[code[b][(((ks << 3) + (q << 2) + i) << 5) + cw] & 255];
                t = MFMA32(a, asbf(w4), t, 0, 0, 0);
            }
            #pragma unroll
            for (int i = 0; i < 16; ++i) acc[i] += scl * t[i];
        }

        // LoRA extension: += (x.A) . B  (K = 16)
        {
            bf16x8 la = bfzero();
            if (s0 + cw < cnt)
                la = *(const bf16x8*)(xA + (size_t)(off + s0 + cw) * NR + (q << 3));
            const float* Bq = Bp + ((size_t)e * NR + (q << 3)) * NI + colg;
            uint4 w4; u32* wp = &w4.x;
            #pragma unroll
            for (int i = 0; i < 4; ++i)
                wp[i] = bfpack2(Bq[(2 * i) * NI], Bq[(2 * i + 1) * NI]);
            acc = MFMA32(la, asbf(w4), acc, 0, 0, 0);
        }
        // epilogue: store bf16 tile. C row = (reg&3) + 8*(reg>>2) + 4*q
        unsigned short* outb = gu + (size_t)mat * NPAIR * NI;
        #pragma unroll
        for (int reg = 0; reg < 16; ++reg) {
            int rloc = (reg & 3) + 8 * (reg >> 2) + (q << 2);
            if (s0 + rloc < cnt)
                outb[(size_t)(off + s0 + rloc) * NI + colg] =
                    (unsigned short)f2bf(acc[reg]);
        }
    }
}

// -------- kernel 5: h = silu(gate)*up --------
__global__ __launch_bounds__(256) void k_swiglu(const unsigned short* __restrict__ gu,
                                                unsigned short* __restrict__ hbuf) {
    int i = (blockIdx.x * 256 + threadIdx.x) * 8;
    uint4 gv = *(const uint4*)(gu + i);
    uint4 uv = *(const uint4*)(gu + (size_t)NPAIR * NI + i);
    const u32* gp = &gv.x; const u32* up = &uv.x;
    uint4 hv; u32* hp = &hv.x;
    #pragma unroll
    for (int j = 0; j < 4; ++j) {
        float g0 = bf2f(gp[j] & 0xFFFFu), g1 = bf2f(gp[j] >> 16);
        float u0 = bf2f(up[j] & 0xFFFFu), u1 = bf2f(up[j] >> 16);
        float h0 = g0 * u0 / (1.f + __expf(-g0));
        float h1 = g1 * u1 / (1.f + __expf(-g1));
        hp[j] = bfpack2(h0, h1);
    }
    *(uint4*)(hbuf + i) = hv;
}

// -------- kernel 6: hA[p][r] = h . down_A --------
__global__ __launch_bounds__(256) void k_hA(const unsigned short* __restrict__ hbuf,
                                            const float* __restrict__ dA,
                                            const int* __restrict__ pexp,
                                            unsigned short* __restrict__ hA) {
    int p = blockIdx.x;
    int e = pexp[p];
    int tid = threadIdx.x;
    int r = tid & 15, ch = tid >> 4;
    const unsigned short* hr = hbuf + (size_t)p * NI;
    const float* dAr = dA + (size_t)e * NI * NR;
    float sv = 0.f;
    for (int j = ch * 64; j < ch * 64 + 64; ++j) {
        float hv = bf2f(hr[j]);
        sv += hv * dAr[j * NR + r];
    }
    __shared__ float red[16][16];
    red[ch][r] = sv;
    __syncthreads();
    for (int st = 8; st >= 1; st >>= 1) {
        if (ch < st) red[ch][r] += red[ch + st][r];
        __syncthreads();
    }
    if (tid < 16) hA[p * NR + tid] = (unsigned short)f2bf(red[0][tid]);
}

// -------- kernel 7: down GEMM (same single-wave vmcnt pipeline) + combine ----
__global__ __launch_bounds__(64) void k_dn(
    const unsigned short* __restrict__ hbuf,
    const int* __restrict__ dpk, const float* __restrict__ dsc,
    const float* __restrict__ dB,
    const unsigned short* __restrict__ hA,
    const int* __restrict__ expert_off, const int* __restrict__ ptok,
    const float* __restrict__ pw,
    float* __restrict__ out)
{
    __shared__ u32 lut[256];
    __shared__ u32 code[3][1024];
    __shared__ unsigned short afrag[3][2048];
    __shared__ float sclb[16][32];

    int lane = threadIdx.x;
    int q = lane >> 5, cw = lane & 31;
    for (int i = lane; i < 256; i += 64)
        lut[i] = bfpack2(NF4_TAB[i & 15], NF4_TAB[(i >> 4) & 15]);

    int e = blockIdx.x;
    int c0 = blockIdx.y * 32;
    int rt = blockIdx.z;                      // 0..3
    const u32* pk = (const u32*)dpk;

    int off = expert_off[e];
    int cnt = expert_off[e + 1] - off;
    int colg = c0 + cw;
    const size_t pkb = (size_t)e * (NI / 2) * NH;

    {
        const float* sg = dsc + (size_t)e * (NI / NGROUP) * NH + c0;
        #pragma unroll
        for (int g = 0; g < 2; ++g)
            stage16(sg + (size_t)(g * 8 + (lane >> 3)) * NH + ((lane & 7) << 2),
                    &sclb[g * 8][0]);
    }

    const int NS = NI / 64;                   // 16 K-steps
    for (int s0 = rt * 32; s0 < cnt; s0 += 128) {
        int rr = s0 + cw; if (rr > cnt - 1) rr = cnt - 1;
        u32 ro = (u32)(off + rr) * (u32)NI;   // compact h rows

        auto stage = [&](int b, int k0) {
            int kp0 = k0 >> 1;
            #pragma unroll
            for (int g = 0; g < 4; ++g)
                stage16(pk + pkb + (size_t)(kp0 + (g << 3) + (lane >> 3)) * NH
                            + c0 + ((lane & 7) << 2),
                        &code[b][g << 8]);
            #pragma unroll
            for (int ks = 0; ks < 4; ++ks)
                stage16(hbuf + ro + k0 + (ks << 4) + (q << 3),
                        &afrag[b][ks << 9]);
        };

        f32x16 acc;
        #pragma unroll
        for (int i = 0; i < 16; ++i) acc[i] = 0.f;

        stage(0, 0);
        stage(1, 64);
        for (int s = 0; s < NS; ++s) {
            if (s + 1 < NS) WAIT_PREV_STAGE(); else WAIT_ALL();
            if (s + 2 < NS) stage((s + 2) % 3, (s + 2) * 64);
            int b = s % 3;
            float scl = sclb[s][cw];
            f32x16 t;
            #pragma unroll
            for (int i = 0; i < 16; ++i) t[i] = 0.f;
            #pragma unroll
            for (int ks = 0; ks < 4; ++ks) {
                bf16x8 a = *(const bf16x8*)&afrag[b][(ks << 9) + (lane << 3)];
                uint4 w4; u32* wp = &w4.x;
                #pragma unroll
                for (int i = 0; i < 4; ++i)
                    wp[i] = lut[code[b][(((ks << 3) + (q << 2) + i) << 5) + cw] & 255];
                t = MFMA32(a, asbf(w4), t, 0, 0, 0);
            }
            #pragma unroll
            for (int i = 0; i < 16; ++i) acc[i] += scl * t[i];
        }

        // LoRA extension: += (h.down_A) . down_B (K = 16)
        {
            bf16x8 la = bfzero();
            if (s0 + cw < cnt)
                la = *(const bf16x8*)(hA + (size_t)(off + s0 + cw) * NR + (q << 3));
            const float* Bq = dB + ((size_t)e * NR + (q << 3)) * NH + colg;
            uint4 w4; u32* wp = &w4.x;
            #pragma unroll
            for (int i = 0; i < 4; ++i)
                wp[i] = bfpack2(Bq[(2 * i) * NH], Bq[(2 * i + 1) * NH]);
            acc = MFMA32(la, asbf(w4), acc, 0, 0, 0);
        }
        // epilogue: weighted atomic combine
        #pragma unroll
        for (int reg = 0; reg < 16; ++reg) {
            int rloc = (reg & 3) + 8 * (reg >> 2) + (q << 2);
            if (s0 + rloc < cnt) {
                int p = off + s0 + rloc;
                atomicAdd(&out[(size_t)ptok[p] * NH + colg], acc[reg] * pw[p]);
            }
        }
    }
}

extern "C" void kernel_launch(void* const* d_in, const int* in_sizes, int n_in,
                              void* d_out, int out_size, void* d_ws,
                              size_t ws_size, hipStream_t stream) {
    const float* x = (const float*)d_in[0];
    const int* topk_idx = (const int*)d_in[1];
    const float* topk_w = (const float*)d_in[2];
    const int* gate_packed = (const int*)d_in[3];
    const float* gate_scales = (const float*)d_in[4];
    const int* up_packed = (const int*)d_in[5];
    const float* up_scales = (const float*)d_in[6];
    const int* down_packed = (const int*)d_in[7];
    const float* down_scales = (const float*)d_in[8];
    const float* gate_A = (const float*)d_in[9];
    const float* gate_B = (const float*)d_in[10];
    const float* up_A = (const float*)d_in[11];
    const float* up_B = (const float*)d_in[12];
    const float* down_A = (const float*)d_in[13];
    const float* down_B = (const float*)d_in[14];
    float* out = (float*)d_out;

    char* ws = (char*)d_ws;
    int* expert_off = (int*)(ws + OFF_EXPOFF);
    int* ptok = (int*)(ws + OFF_TOK);
    int* pexp = (int*)(ws + OFF_EXP);
    float* pw = (float*)(ws + OFF_W);
    unsigned short* xAg = (unsigned short*)(ws + OFF_XAG);
    unsigned short* xAu = (unsigned short*)(ws + OFF_XAU);
    unsigned short* hA = (unsigned short*)(ws + OFF_HA);
    unsigned short* xb = (unsigned short*)(ws + OFF_XB);
    unsigned short* gu = (unsigned short*)(ws + OFF_GU);
    unsigned short* hbuf = (unsigned short*)(ws + OFF_HBUF);

    hipMemsetAsync(d_out, 0, (size_t)NT * NH * sizeof(float), stream);

    k_route<<<1, 1024, 0, stream>>>(topk_idx, topk_w, expert_off, ptok, pexp, pw);
    k_xcvt<<<(NT * NH) / (256 * 8), 256, 0, stream>>>(x, xb);
    k_xA<<<NPAIR, 256, 0, stream>>>(x, gate_A, up_A, ptok, pexp, xAg, xAu);
    k_gu<<<dim3(NE, NI / 32, 8), 64, 0, stream>>>(
        xb, gate_packed, gate_scales, up_packed, up_scales, gate_B, up_B,
        xAg, xAu, expert_off, ptok, gu);
    k_swiglu<<<(NPAIR * NI) / (256 * 8), 256, 0, stream>>>(gu, hbuf);
    k_hA<<<NPAIR, 256, 0, stream>>>(hbuf, down_A, pexp, hA);
    k_dn<<<dim3(NE, NH / 32, 4), 64, 0, stream>>>(
        hbuf, down_packed, down_scales, down_B, hA, expert_off, ptok, pw, out);
}